// Round 1
// baseline (1015.828 us; speedup 1.0000x reference)
//
#include <hip/hip_runtime.h>
#include <math.h>

#define NND 50000
#define DEG 16

// ---- workspace layout (bytes, 256-aligned) ----
// [0, 76.8M)  GX  (N x 384)   -- walk-phase aliases: h_pre @0 (N x 64), proj @12.8M (N x 64)
#define OFF_PROJ 12800000ULL
#define OFF_IDX  76800000ULL   // 5*N ints
#define OFF_CUR  77800192ULL   // N ints
#define OFF_HA   78000384ULL   // N x 128 f32
#define OFF_HB   103600384ULL  // N x 128 f32
#define OFF_WHQ  129200384ULL  // 128 x 512 f32
#define WS_NEED  129462528ULL

__device__ __forceinline__ float sigf(float x){ return 1.0f/(1.0f + expf(-x)); }

__global__ __launch_bounds__(256) void k_iota(int* __restrict__ cur, int* __restrict__ idx0){
    int i = blockIdx.x*256 + threadIdx.x;
    if (i < NND){ cur[i] = i; idx0[i] = i; }
}

// out(N x 64) = A(N x 128) @ B(128 x 64) [+ bias]; BM=64 BN=64 KC=32
__global__ __launch_bounds__(256) void k_proj(const float* __restrict__ A,
    const float* __restrict__ B, const float* __restrict__ bias,
    float* __restrict__ out)
{
    __shared__ float Al[64][33];
    __shared__ float Bl[32][68];
    const int tid = threadIdx.x;
    const int row0 = blockIdx.x << 6;
    const int row_t = tid >> 4, col_t = tid & 15;
    float4 acc[4];
#pragma unroll
    for (int i=0;i<4;i++) acc[i] = make_float4(0.f,0.f,0.f,0.f);
    for (int k0 = 0; k0 < 128; k0 += 32){
#pragma unroll
        for (int r=0;r<2;r++){
            int am = (tid>>3) + (r<<5);
            int ak = (tid&7) << 2;
            int gr = row0 + am; if (gr >= NND) gr = NND-1;
            float4 v = *(const float4*)(A + (size_t)gr*128 + k0 + ak);
            Al[am][ak] = v.x; Al[am][ak+1] = v.y; Al[am][ak+2] = v.z; Al[am][ak+3] = v.w;
        }
#pragma unroll
        for (int r=0;r<2;r++){
            int p = (r<<8) + tid;
            int bk = p >> 4, bc = (p & 15) << 2;
            *(float4*)(&Bl[bk][bc]) = *(const float4*)(B + (size_t)(k0+bk)*64 + bc);
        }
        __syncthreads();
#pragma unroll 8
        for (int k=0;k<32;k++){
            float4 b = *(const float4*)(&Bl[k][col_t<<2]);
#pragma unroll
            for (int i=0;i<4;i++){
                float a = Al[(row_t<<2)+i][k];
                acc[i].x = fmaf(a, b.x, acc[i].x);
                acc[i].y = fmaf(a, b.y, acc[i].y);
                acc[i].z = fmaf(a, b.z, acc[i].z);
                acc[i].w = fmaf(a, b.w, acc[i].w);
            }
        }
        __syncthreads();
    }
    float4 bb = make_float4(0.f,0.f,0.f,0.f);
    if (bias) bb = *(const float4*)(bias + (col_t<<2));
#pragma unroll
    for (int i=0;i<4;i++){
        int gr = row0 + (row_t<<2) + i;
        if (gr < NND){
            float4 o = make_float4(acc[i].x+bb.x, acc[i].y+bb.y, acc[i].z+bb.z, acc[i].w+bb.w);
            *(float4*)(out + (size_t)gr*64 + (col_t<<2)) = o;
        }
    }
}

// one walk step: 16 nodes/block, thread <-> (node, d)
__global__ __launch_bounds__(256) void k_walk(float* __restrict__ hpre,
    const float* __restrict__ proj, const int* __restrict__ dst,
    const float* __restrict__ W2, const float* __restrict__ b2,
    const float* __restrict__ noi, int* __restrict__ cur,
    int* __restrict__ idxo)
{
    __shared__ float hp_l[1024];
    __shared__ float w2_l[64];
    __shared__ int   nv_l[16];
    const int tid = threadIdx.x;
    const int nl = tid >> 4, d = tid & 15;
    const int gi0 = blockIdx.x << 4;
    const int gi = gi0 + nl;
    *(float4*)(hp_l + (tid<<2)) = *(const float4*)(hpre + ((size_t)gi0<<6) + (tid<<2));
    if (tid < 64) w2_l[tid] = W2[tid];
    __syncthreads();
    const int ci  = cur[gi];
    const int nbr = dst[ci*DEG + d];
    float lp = b2[0];
    const float* pj = proj + ((size_t)nbr<<6);
    const float* hh = hp_l + (nl<<6);
#pragma unroll
    for (int h=0; h<64; h+=4){
        float4 p4 = *(const float4*)(pj + h);
        float4 h4 = *(const float4*)(hh + h);
        float4 w4 = *(const float4*)(w2_l + h);
        lp = fmaf(fmaxf(h4.x+p4.x,0.f), w4.x, lp);
        lp = fmaf(fmaxf(h4.y+p4.y,0.f), w4.y, lp);
        lp = fmaf(fmaxf(h4.z+p4.z,0.f), w4.z, lp);
        lp = fmaf(fmaxf(h4.w+p4.w,0.f), w4.w, lp);
    }
    // softmax over the 16-lane group (matches np: exp(x - (m + log s)))
    float mx = lp;
#pragma unroll
    for (int off=8; off; off>>=1) mx = fmaxf(mx, __shfl_xor(mx, off, 16));
    float s = expf(lp - mx);
#pragma unroll
    for (int off=8; off; off>>=1) s += __shfl_xor(s, off, 16);
    float p = expf(lp - mx - logf(s)) + noi[((size_t)gi<<4) + d];
    // argmax, first-index tie-break
    float bv = p; int bi = d;
#pragma unroll
    for (int off=8; off; off>>=1){
        float ov = __shfl_xor(bv, off, 16);
        int   oi = __shfl_xor(bi, off, 16);
        if (ov > bv || (ov == bv && oi < bi)){ bv = ov; bi = oi; }
    }
    int sn = __shfl(nbr, bi, 16);
    if (d == 0){ cur[gi] = sn; idxo[gi] = sn; nv_l[nl] = sn; }
    __syncthreads();
    // h_pre += proj[selected]
    const int n2 = tid >> 4;
    const int h4i = (tid & 15) << 2;
    const int v = nv_l[n2];
    float4 u  = *(const float4*)(proj + ((size_t)v<<6) + h4i);
    float4 hp = *(const float4*)(hp_l + (n2<<6) + h4i);
    hp.x += u.x; hp.y += u.y; hp.z += u.z; hp.w += u.w;
    *(float4*)(hpre + ((size_t)(gi0+n2)<<6) + h4i) = hp;
}

// GX(N x 384) = A(N x 128) @ Wx(128 x 384) + bx ; BM=32 BN=128, grid.y=3
__global__ __launch_bounds__(256) void k_gxall(const float* __restrict__ A,
    const float* __restrict__ Wx, const float* __restrict__ bx,
    float* __restrict__ GX)
{
    __shared__ float Al[32][33];
    __shared__ float Bl[32][132];
    const int tid = threadIdx.x;
    const int row0 = blockIdx.x << 5;
    const int cb = blockIdx.y << 7;
    const int row_t = tid >> 5, col_t = tid & 31;
    float4 acc[4];
#pragma unroll
    for (int i=0;i<4;i++) acc[i] = make_float4(0.f,0.f,0.f,0.f);
    for (int k0 = 0; k0 < 128; k0 += 32){
        {
            int am = tid >> 3, ak = (tid & 7) << 2;
            int gr = row0 + am; if (gr >= NND) gr = NND-1;
            float4 v = *(const float4*)(A + (size_t)gr*128 + k0 + ak);
            Al[am][ak] = v.x; Al[am][ak+1] = v.y; Al[am][ak+2] = v.z; Al[am][ak+3] = v.w;
        }
#pragma unroll
        for (int r=0;r<4;r++){
            int bk = (tid>>5) + (r<<3);
            int bc = (tid&31) << 2;
            *(float4*)(&Bl[bk][bc]) = *(const float4*)(Wx + (size_t)(k0+bk)*384 + cb + bc);
        }
        __syncthreads();
#pragma unroll 8
        for (int k=0;k<32;k++){
            float4 b = *(const float4*)(&Bl[k][col_t<<2]);
#pragma unroll
            for (int i=0;i<4;i++){
                float a = Al[(row_t<<2)+i][k];
                acc[i].x = fmaf(a, b.x, acc[i].x);
                acc[i].y = fmaf(a, b.y, acc[i].y);
                acc[i].z = fmaf(a, b.z, acc[i].z);
                acc[i].w = fmaf(a, b.w, acc[i].w);
            }
        }
        __syncthreads();
    }
    float4 bb = *(const float4*)(bx + cb + (col_t<<2));
#pragma unroll
    for (int i=0;i<4;i++){
        int gr = row0 + (row_t<<2) + i;
        if (gr < NND){
            float4 o = make_float4(acc[i].x+bb.x, acc[i].y+bb.y, acc[i].z+bb.z, acc[i].w+bb.w);
            *(float4*)(GX + (size_t)gr*384 + cb + (col_t<<2)) = o;
        }
    }
}

// Whq[k][4j+g] = g<3 ? Wh[k][g*128+j] : 0
__global__ __launch_bounds__(256) void k_whq(const float* __restrict__ Wh, float* __restrict__ Whq){
    int i = blockIdx.x*256 + threadIdx.x;    // 128*512 = 65536
    int k = i >> 9, q = i & 511, j = q >> 2, g = q & 3;
    Whq[i] = (g < 3) ? Wh[k*384 + g*128 + j] : 0.f;
}

// one GRU step: gh = h_in @ Whq (K=128), fused gate epilogue. BM=32 BN=128, grid.y=4
__global__ __launch_bounds__(256) void k_gru(const float* __restrict__ h_in,
    const float* __restrict__ Whq, const float* __restrict__ GX,
    const float* __restrict__ bh, const int* __restrict__ xidx,
    float* __restrict__ h_out, const int first)
{
    __shared__ float Al[32][33];
    __shared__ float Bl[32][132];
    const int tid = threadIdx.x;
    const int row0 = blockIdx.x << 5;
    const int cb = blockIdx.y << 7;
    const int row_t = tid >> 5, col_t = tid & 31;
    float4 acc[4];
#pragma unroll
    for (int i=0;i<4;i++) acc[i] = make_float4(0.f,0.f,0.f,0.f);
    if (!first){
        for (int k0 = 0; k0 < 128; k0 += 32){
            {
                int am = tid >> 3, ak = (tid & 7) << 2;
                int gr = row0 + am; if (gr >= NND) gr = NND-1;
                float4 v = *(const float4*)(h_in + (size_t)gr*128 + k0 + ak);
                Al[am][ak] = v.x; Al[am][ak+1] = v.y; Al[am][ak+2] = v.z; Al[am][ak+3] = v.w;
            }
#pragma unroll
            for (int r=0;r<4;r++){
                int bk = (tid>>5) + (r<<3);
                int bc = (tid&31) << 2;
                *(float4*)(&Bl[bk][bc]) = *(const float4*)(Whq + (size_t)(k0+bk)*512 + cb + bc);
            }
            __syncthreads();
#pragma unroll 8
            for (int k=0;k<32;k++){
                float4 b = *(const float4*)(&Bl[k][col_t<<2]);
#pragma unroll
                for (int i=0;i<4;i++){
                    float a = Al[(row_t<<2)+i][k];
                    acc[i].x = fmaf(a, b.x, acc[i].x);
                    acc[i].y = fmaf(a, b.y, acc[i].y);
                    acc[i].z = fmaf(a, b.z, acc[i].z);
                    acc[i].w = fmaf(a, b.w, acc[i].w);
                }
            }
            __syncthreads();
        }
    }
    const int j = (blockIdx.y << 5) + col_t;   // gate index 0..127
    const float bhr = bh[j], bhz = bh[128+j], bhn = bh[256+j];
#pragma unroll
    for (int i=0;i<4;i++){
        int gr = row0 + (row_t<<2) + i;
        if (gr < NND){
            int xv = xidx[gr];
            const float* g = GX + (size_t)xv*384;
            float rr = sigf(g[j]       + acc[i].x + bhr);
            float zz = sigf(g[128+j]   + acc[i].y + bhz);
            float nn = tanhf(g[256+j]  + rr*(acc[i].z + bhn));
            float hold = first ? 0.f : h_in[(size_t)gr*128 + j];
            h_out[(size_t)gr*128 + j] = (1.f - zz)*nn + zz*hold;
        }
    }
}

// out(N x 128) = h(N x 128) @ Wo(128 x 128) + bo
__global__ __launch_bounds__(256) void k_out(const float* __restrict__ H,
    const float* __restrict__ Wo, const float* __restrict__ bo,
    float* __restrict__ out)
{
    __shared__ float Al[32][33];
    __shared__ float Bl[32][132];
    const int tid = threadIdx.x;
    const int row0 = blockIdx.x << 5;
    const int row_t = tid >> 5, col_t = tid & 31;
    float4 acc[4];
#pragma unroll
    for (int i=0;i<4;i++) acc[i] = make_float4(0.f,0.f,0.f,0.f);
    for (int k0 = 0; k0 < 128; k0 += 32){
        {
            int am = tid >> 3, ak = (tid & 7) << 2;
            int gr = row0 + am; if (gr >= NND) gr = NND-1;
            float4 v = *(const float4*)(H + (size_t)gr*128 + k0 + ak);
            Al[am][ak] = v.x; Al[am][ak+1] = v.y; Al[am][ak+2] = v.z; Al[am][ak+3] = v.w;
        }
#pragma unroll
        for (int r=0;r<4;r++){
            int bk = (tid>>5) + (r<<3);
            int bc = (tid&31) << 2;
            *(float4*)(&Bl[bk][bc]) = *(const float4*)(Wo + (size_t)(k0+bk)*128 + bc);
        }
        __syncthreads();
#pragma unroll 8
        for (int k=0;k<32;k++){
            float4 b = *(const float4*)(&Bl[k][col_t<<2]);
#pragma unroll
            for (int i=0;i<4;i++){
                float a = Al[(row_t<<2)+i][k];
                acc[i].x = fmaf(a, b.x, acc[i].x);
                acc[i].y = fmaf(a, b.y, acc[i].y);
                acc[i].z = fmaf(a, b.z, acc[i].z);
                acc[i].w = fmaf(a, b.w, acc[i].w);
            }
        }
        __syncthreads();
    }
    float4 bb = *(const float4*)(bo + (col_t<<2));
#pragma unroll
    for (int i=0;i<4;i++){
        int gr = row0 + (row_t<<2) + i;
        if (gr < NND){
            float4 o = make_float4(acc[i].x+bb.x, acc[i].y+bb.y, acc[i].z+bb.z, acc[i].w+bb.w);
            *(float4*)(out + (size_t)gr*128 + (col_t<<2)) = o;
        }
    }
}

extern "C" void kernel_launch(void* const* d_in, const int* in_sizes, int n_in,
                              void* d_out, int out_size, void* d_ws, size_t ws_size,
                              hipStream_t stream)
{
    const float* node_attr = (const float*)d_in[0];
    const int*   edge_index= (const int*)  d_in[1];
    // d_in[2] = slices: slices[i,0] == i*DEG by construction -> not needed
    const float* noise = (const float*)d_in[3];
    const float* W1 = (const float*)d_in[4];
    const float* b1 = (const float*)d_in[5];
    const float* W2 = (const float*)d_in[6];
    const float* b2 = (const float*)d_in[7];
    const float* Wx = (const float*)d_in[8];
    const float* Wh = (const float*)d_in[9];
    const float* bx = (const float*)d_in[10];
    const float* bh = (const float*)d_in[11];
    const float* Wo = (const float*)d_in[12];
    const float* bo = (const float*)d_in[13];
    const int* dst = edge_index + (size_t)NND*DEG;   // row 1 of (2, N*D)
    float* out = (float*)d_out;
    if (ws_size < WS_NEED) return;

    char* ws = (char*)d_ws;
    float* GX   = (float*)(ws);
    float* hpre = (float*)(ws);              // alias: dead before GX written
    float* proj = (float*)(ws + OFF_PROJ);   // alias: dead before GX written
    int*   idxb = (int*)  (ws + OFF_IDX);
    int*   cur  = (int*)  (ws + OFF_CUR);
    float* hA   = (float*)(ws + OFF_HA);
    float* hB   = (float*)(ws + OFF_HB);
    float* Whq  = (float*)(ws + OFF_WHQ);

    k_iota<<<dim3(196), dim3(256), 0, stream>>>(cur, idxb);
    // h_pre init = b1 + A @ W1[0:128]
    k_proj<<<dim3(782), dim3(256), 0, stream>>>(node_attr, W1, b1, hpre);
    for (int t = 0; t < 4; t++){
        k_proj<<<dim3(782), dim3(256), 0, stream>>>(node_attr, W1 + (size_t)(1+t)*128*64, nullptr, proj);
        k_walk<<<dim3(3125), dim3(256), 0, stream>>>(hpre, proj, dst, W2, b2,
                 noise + (size_t)t*NND*DEG, cur, idxb + (size_t)(t+1)*NND);
    }
    // GX = node_attr @ Wx + bx  (overwrites hpre/proj region -- they are dead now)
    k_gxall<<<dim3(1563,3), dim3(256), 0, stream>>>(node_attr, Wx, bx, GX);
    k_whq<<<dim3(256), dim3(256), 0, stream>>>(Wh, Whq);
    for (int s = 0; s < 5; s++){
        const float* hi = (s & 1) ? hA : hB;
        float*       ho = (s & 1) ? hB : hA;
        k_gru<<<dim3(1563,4), dim3(256), 0, stream>>>(hi, Whq, GX, bh,
                 idxb + (size_t)s*NND, ho, s==0 ? 1 : 0);
    }
    k_out<<<dim3(1563), dim3(256), 0, stream>>>(hA, Wo, bo, out);
}